// Round 5
// baseline (416.942 us; speedup 1.0000x reference)
//
#include <hip/hip_runtime.h>

// Pin2PinAttraction: sum_i w[i] * ((x[a_i]-x[b_i])^2 + (y[a_i]-y[b_i])^2)
//
// r5 = r4 with compile fix: ext_vector i32x2 instead of HIP int2 for
// __builtin_nontemporal_load (builtin rejects HIP_vector_type classes).
//
// Strategy: 2-D binning for L2 residency.
//   - pack x/y into interleaved float2 xy[] (16 MB) in ws  [r3 win, kept]
//   - bin pairs by (a>>shift, b>>shift) into 8x8=64 bins (2 MB slices)
//   - gather pass: XCD i (blockIdx&7) processes only bins (i, j), j=0..7 in
//     order -> its 4 MB L2 holds slice_i + slice_j concurrently -> ~all hits.
//   - bin overflow (statistically impossible at cap>=160k, but guarded):
//     computed directly in the scatter kernel => always correct.
//   - ws too small => fall back to the r3 single-pass gather.

typedef int   i32x4 __attribute__((ext_vector_type(4)));
typedef int   i32x2 __attribute__((ext_vector_type(2)));
typedef float f32x2 __attribute__((ext_vector_type(2)));

// ---------------------------------------------------------------- pack
__global__ __launch_bounds__(256) void pack_xy_kernel(
    const float* __restrict__ pin_pos,
    f32x2*       __restrict__ xy,
    int num_pins)
{
    const int tid    = blockIdx.x * blockDim.x + threadIdx.x;
    const int stride = gridDim.x * blockDim.x;
    const float* __restrict__ xs = pin_pos;
    const float* __restrict__ ys = pin_pos + num_pins;
    for (int i = tid; i < num_pins; i += stride) {
        f32x2 v; v.x = xs[i]; v.y = ys[i];
        xy[i] = v;
    }
}

// ---------------------------------------------------------------- scatter/bin
// Per block: (1) LDS histogram of 64 bins over its chunk, one global
// atomicAdd per (block,bin) reserving a contiguous range, (2) rank via LDS
// atomics and write (a,b)+w into the bin arrays. Overflow entries are
// computed immediately (correctness never depends on cap).
__global__ __launch_bounds__(256) void scatter_bin_kernel(
    const int*   __restrict__ pairs,    // [2*num_pairs] interleaved
    const float* __restrict__ weights,  // [num_pairs]
    const f32x2* __restrict__ xy,       // packed table (overflow path)
    i32x2*       __restrict__ ab_out,   // [64*cap]
    float*       __restrict__ w_out,    // [64*cap]
    int*         __restrict__ cursors,  // [64], zeroed
    float*       __restrict__ out,
    int num_pairs, int shift, int cap)
{
    const int tid = threadIdx.x;
    const long start = (long)num_pairs * blockIdx.x / gridDim.x;
    const long end   = (long)num_pairs * (blockIdx.x + 1) / gridDim.x;

    const i32x2* __restrict__ pr = (const i32x2*)pairs;

    __shared__ int hist[64];
    __shared__ int base_s[64];

    if (tid < 64) hist[tid] = 0;
    __syncthreads();

    // pass 1: count (loads stay L2-warm for pass 2)
    for (long i = start + tid; i < end; i += 256) {
        i32x2 p = pr[i];
        int bin = ((p.x >> shift) << 3) | (p.y >> shift);
        atomicAdd(&hist[bin], 1);
    }
    __syncthreads();

    if (tid < 64) {
        base_s[tid] = atomicAdd(&cursors[tid], hist[tid]);
        hist[tid] = 0;  // reuse as running rank
    }
    __syncthreads();

    // pass 2: rank + write
    float facc = 0.0f;  // overflow fallback accumulator (normally 0)
    for (long i = start + tid; i < end; i += 256) {
        i32x2 p = pr[i];
        float w = weights[i];
        int bin = ((p.x >> shift) << 3) | (p.y >> shift);
        int r = atomicAdd(&hist[bin], 1);
        long pos = (long)base_s[bin] + r;
        if (pos < cap) {
            ab_out[(long)bin * cap + pos] = p;
            w_out [(long)bin * cap + pos] = w;
        } else {
            f32x2 A = xy[p.x], B = xy[p.y];
            float dx = A.x - B.x, dy = A.y - B.y;
            facc += w * (dx * dx + dy * dy);
        }
    }

    // reduce the (normally zero) overflow contributions
    for (int off = 32; off > 0; off >>= 1)
        facc += __shfl_down(facc, off, 64);
    __shared__ float wave_sums[4];
    const int lane = tid & 63, wid = tid >> 6;
    if (lane == 0) wave_sums[wid] = facc;
    __syncthreads();
    if (tid == 0) {
        float s = wave_sums[0] + wave_sums[1] + wave_sums[2] + wave_sums[3];
        if (s != 0.0f) atomicAdd(out, s);
    }
}

// ---------------------------------------------------------------- gather (binned)
__global__ __launch_bounds__(256) void gather_binned_kernel(
    const f32x2* __restrict__ xy,
    const i32x2* __restrict__ ab,
    const float* __restrict__ wbin,
    const int*   __restrict__ cursors,
    float*       __restrict__ out,
    int cap)
{
    const int tid = threadIdx.x;
    const int xcd = blockIdx.x & 7;   // assumed round-robin WG->XCD mapping
    const int lb  = blockIdx.x >> 3;  // local block id within the XCD group
    const int nlb = gridDim.x >> 3;

    float acc = 0.0f;

    for (int j = 0; j < 8; ++j) {     // j-ordered: all XCD-i blocks share slice_j
        const int bin = xcd * 8 + j;
        int cnt = cursors[bin];
        if (cnt > cap) cnt = cap;
        const int k0 = (int)((long)cnt * lb / nlb);
        const int k1 = (int)((long)cnt * (lb + 1) / nlb);
        const i32x2* __restrict__ abp = ab   + (long)bin * cap;
        const float* __restrict__ wp  = wbin + (long)bin * cap;
        for (int k = k0 + tid; k < k1; k += 256) {
            i32x2 p = __builtin_nontemporal_load(abp + k);
            float w = __builtin_nontemporal_load(wp + k);
            f32x2 A = xy[p.x], B = xy[p.y];
            float dx = A.x - B.x, dy = A.y - B.y;
            acc += w * (dx * dx + dy * dy);
        }
    }

    for (int off = 32; off > 0; off >>= 1)
        acc += __shfl_down(acc, off, 64);
    __shared__ float wave_sums[4];
    const int lane = tid & 63, wid = tid >> 6;
    if (lane == 0) wave_sums[wid] = acc;
    __syncthreads();
    if (tid == 0) {
        float s = wave_sums[0] + wave_sums[1] + wave_sums[2] + wave_sums[3];
        atomicAdd(out, s);
    }
}

// ---------------------------------------------------------------- r3 fallback
__global__ __launch_bounds__(256) void p2p_gather_kernel(
    const f32x2* __restrict__ xy,
    const float* __restrict__ weights,
    const int*   __restrict__ pairs,
    float*       __restrict__ out,
    int num_pairs)
{
    const int tid    = blockIdx.x * blockDim.x + threadIdx.x;
    const int stride = gridDim.x * blockDim.x;
    float acc = 0.0f;
    const i32x4* __restrict__ pairs4 = (const i32x4*)pairs;
    const f32x2* __restrict__ w2     = (const f32x2*)weights;
    const int n2 = num_pairs >> 1;
    for (int i = tid; i < n2; i += stride) {
        i32x4 p = __builtin_nontemporal_load(pairs4 + i);
        f32x2 w = __builtin_nontemporal_load(w2 + i);
        f32x2 A0 = xy[p.x], B0 = xy[p.y];
        f32x2 A1 = xy[p.z], B1 = xy[p.w];
        float dx0 = A0.x - B0.x, dy0 = A0.y - B0.y;
        float dx1 = A1.x - B1.x, dy1 = A1.y - B1.y;
        acc += w.x * (dx0 * dx0 + dy0 * dy0);
        acc += w.y * (dx1 * dx1 + dy1 * dy1);
    }
    if ((num_pairs & 1) && tid == 0) {
        int a = pairs[2 * (num_pairs - 1)];
        int b = pairs[2 * (num_pairs - 1) + 1];
        f32x2 A = xy[a], B = xy[b];
        float dx = A.x - B.x, dy = A.y - B.y;
        acc += weights[num_pairs - 1] * (dx * dx + dy * dy);
    }
    for (int off = 32; off > 0; off >>= 1)
        acc += __shfl_down(acc, off, 64);
    __shared__ float wave_sums[4];
    const int lane = threadIdx.x & 63, wid = threadIdx.x >> 6;
    if (lane == 0) wave_sums[wid] = acc;
    __syncthreads();
    if (threadIdx.x == 0) {
        float s = wave_sums[0] + wave_sums[1] + wave_sums[2] + wave_sums[3];
        atomicAdd(out, s);
    }
}

// ---------------------------------------------------------------- direct (no-ws)
__global__ __launch_bounds__(256) void p2p_direct_kernel(
    const float* __restrict__ pin_pos,
    const float* __restrict__ weights,
    const int*   __restrict__ pairs,
    float*       __restrict__ out,
    int num_pins, int num_pairs)
{
    const float* __restrict__ xs = pin_pos;
    const float* __restrict__ ys = pin_pos + num_pins;
    const int tid    = blockIdx.x * blockDim.x + threadIdx.x;
    const int stride = gridDim.x * blockDim.x;
    float acc = 0.0f;
    for (int i = tid; i < num_pairs; i += stride) {
        int a = pairs[2 * i], b = pairs[2 * i + 1];
        float dx = xs[a] - xs[b], dy = ys[a] - ys[b];
        acc += weights[i] * (dx * dx + dy * dy);
    }
    for (int off = 32; off > 0; off >>= 1)
        acc += __shfl_down(acc, off, 64);
    __shared__ float wave_sums[4];
    const int lane = threadIdx.x & 63, wid = threadIdx.x >> 6;
    if (lane == 0) wave_sums[wid] = acc;
    __syncthreads();
    if (threadIdx.x == 0) {
        float s = wave_sums[0] + wave_sums[1] + wave_sums[2] + wave_sums[3];
        atomicAdd(out, s);
    }
}

// ---------------------------------------------------------------- launch
extern "C" void kernel_launch(void* const* d_in, const int* in_sizes, int n_in,
                              void* d_out, int out_size, void* d_ws, size_t ws_size,
                              hipStream_t stream) {
    const float* pin_pos = (const float*)d_in[0];
    const float* weights = (const float*)d_in[1];
    const int*   pairs   = (const int*)d_in[2];

    const int num_pins  = in_sizes[0] / 2;
    const int num_pairs = in_sizes[1];

    float* out = (float*)d_out;
    hipMemsetAsync(out, 0, sizeof(float), stream);  // d_out poisoned each call

    const int block = 256;

    // slice shift: (num_pins-1)>>shift must be <= 7  (8 slices)
    int shift = 0;
    while (((unsigned)(num_pins - 1) >> shift) > 7u) ++shift;

    // ws layout: [xy 8B*num_pins][cursors 256B][ab 8B*64*cap][w 4B*64*cap]
    const size_t xy_bytes = (size_t)num_pins * sizeof(f32x2);
    const size_t cur_off  = (xy_bytes + 255) & ~(size_t)255;
    const size_t ab_off   = cur_off + 256;

    long cap = 0;
    if (ws_size > ab_off) cap = (long)((ws_size - ab_off) / (64 * 12));
    if (cap > 250000) cap = 250000;

    if (cap >= 160000) {  // need headroom over expected max bin ~137.5k
        f32x2* xy      = (f32x2*)d_ws;
        int*   cursors = (int*)((char*)d_ws + cur_off);
        i32x2* ab      = (i32x2*)((char*)d_ws + ab_off);
        float* wbin    = (float*)((char*)d_ws + ab_off + (size_t)64 * cap * sizeof(i32x2));

        hipMemsetAsync(cursors, 0, 64 * sizeof(int), stream);
        pack_xy_kernel<<<2048, block, 0, stream>>>(pin_pos, xy, num_pins);
        scatter_bin_kernel<<<1024, block, 0, stream>>>(
            pairs, weights, xy, ab, wbin, cursors, out,
            num_pairs, shift, (int)cap);
        gather_binned_kernel<<<2048, block, 0, stream>>>(
            xy, ab, wbin, cursors, out, (int)cap);
    } else if (ws_size >= xy_bytes) {
        f32x2* xy = (f32x2*)d_ws;
        pack_xy_kernel<<<2048, block, 0, stream>>>(pin_pos, xy, num_pins);
        p2p_gather_kernel<<<2048, block, 0, stream>>>(
            xy, weights, pairs, out, num_pairs);
    } else {
        p2p_direct_kernel<<<2048, block, 0, stream>>>(
            pin_pos, weights, pairs, out, num_pins, num_pairs);
    }
}